// Round 1
// baseline (1738.841 us; speedup 1.0000x reference)
//
#include <hip/hip_runtime.h>
#include <hip/hip_bf16.h>

// ANI species-expert MLP, fused. Pipeline per launch:
//   memset hdr + energies
//   k_count/k_scan/k_scatter : counting-sort atom indices by species
//   k_wcvt x3                : W1..W3 fp32 [S][K][N] -> bf16 transposed [S][N][K]
//   k_species                : species -> float into d_out[0:N]
//   k_mlp                    : per 64-atom same-species tile, 4-layer MFMA MLP,
//                              atomicAdd per-atom energy into d_out[N:N+2048]

#define NSP   4
#define DIM   384
#define NH1   160
#define NH2   128
#define NH3   96
#define NATOM (2048 * 64)
#define NCONF 2048

typedef __attribute__((ext_vector_type(8))) short short8;
typedef __attribute__((ext_vector_type(4))) float f32x4;

__device__ __forceinline__ unsigned short f2bf(float f) {
  union { float f; unsigned u; } v; v.f = f;
  unsigned r = v.u + 0x7fffu + ((v.u >> 16) & 1u);   // RNE
  return (unsigned short)(r >> 16);
}
__device__ __forceinline__ float bf2f(unsigned short h) {
  union { unsigned u; float f; } v; v.u = ((unsigned)h) << 16;
  return v.f;
}

// ---------------- sort / convert helpers ----------------

__global__ void k_count(const int* __restrict__ sp, int* __restrict__ hdr) {
  int i = blockIdx.x * 256 + threadIdx.x;
  if (i < NATOM) atomicAdd(&hdr[sp[i]], 1);
}

// hdr layout (ints): [0..3] counts, [4..8] real offsets, [9..13] padded offsets,
//                    [14..17] scatter cursors
__global__ void k_scan(int* hdr) {
  if (threadIdx.x == 0 && blockIdx.x == 0) {
    int ro = 0, po = 0;
    for (int s = 0; s < NSP; ++s) {
      hdr[4 + s]  = ro;
      hdr[9 + s]  = po;
      hdr[14 + s] = ro;
      int cs = hdr[s];
      ro += cs;
      po += (cs + 63) & ~63;
    }
    hdr[8]  = ro;
    hdr[13] = po;
  }
}

__global__ void k_scatter(const int* __restrict__ sp, int* __restrict__ hdr,
                          int* __restrict__ sorted) {
  int i = blockIdx.x * 256 + threadIdx.x;
  if (i < NATOM) {
    int s = sp[i];
    int p = atomicAdd(&hdr[14 + s], 1);
    sorted[p] = i;
  }
}

// dst[s][n][k] = bf16(src[s][k][n])
__global__ void k_wcvt(const float* __restrict__ src, unsigned short* __restrict__ dst,
                       int K, int N, int total) {
  int i = blockIdx.x * 256 + threadIdx.x;
  if (i < total) {
    int kn = K * N;
    int s = i / kn, r = i - s * kn;
    int n = r / K, k = r - n * K;
    dst[i] = f2bf(src[s * kn + k * N + n]);
  }
}

__global__ void k_species(const int* __restrict__ sp, float* __restrict__ out) {
  int i = blockIdx.x * 256 + threadIdx.x;
  if (i < NATOM) out[i] = (float)sp[i];
}

// ---------------- fused MLP ----------------

// One 16x16 col-frag set per wave (f = wave, wave+4, ...), all 4 row-frags.
// A (LDS, bf16 [64][K]) -> 4x ds_read_b128 per k-step.
// B from GLOBAL pre-transposed bf16 [NOUT][K]: one dwordx4 per frag (L2-cached,
// 16 full cache lines per wave instruction). No LDS staging for B, no k-loop syncs.
template <int K, int NOUT, bool DOCELU>
__device__ __forceinline__ void layer(const unsigned short* __restrict__ sIn,
                                      const unsigned short* __restrict__ Wt,
                                      const float* __restrict__ bias,
                                      unsigned short* __restrict__ sOut,
                                      int wave, int lane) {
  constexpr int NF = NOUT / 16;
  constexpr int NOWN = (NF + 3) / 4;
  const int c = lane & 15, q = lane >> 4;
  const int kb = q * 8;

  f32x4 acc[4][NOWN];
#pragma unroll
  for (int m = 0; m < 4; ++m)
#pragma unroll
    for (int i = 0; i < NOWN; ++i) acc[m][i] = (f32x4){0.f, 0.f, 0.f, 0.f};

  for (int k0 = 0; k0 < K; k0 += 32) {
    short8 a[4];
#pragma unroll
    for (int m = 0; m < 4; ++m)
      a[m] = *(const short8*)(sIn + (m * 16 + c) * K + k0 + kb);
#pragma unroll
    for (int i = 0; i < NOWN; ++i) {
      int f = wave + 4 * i;
      if (f < NF) {
        short8 b = *(const short8*)(Wt + (f * 16 + c) * K + k0 + kb);
#pragma unroll
        for (int m = 0; m < 4; ++m)
          acc[m][i] = __builtin_amdgcn_mfma_f32_16x16x32_bf16(a[m], b, acc[m][i], 0, 0, 0);
      }
    }
  }

  // epilogue: bias + CELU(alpha=0.1), bf16 -> LDS
  // D layout: col = lane&15 (+16f), row = 4*(lane>>4)+j (+16m)   [m89-verified]
#pragma unroll
  for (int i = 0; i < NOWN; ++i) {
    int f = wave + 4 * i;
    if (f < NF) {
      int col = f * 16 + c;
      float bv = bias[col];
#pragma unroll
      for (int m = 0; m < 4; ++m) {
#pragma unroll
        for (int j = 0; j < 4; ++j) {
          float v = acc[m][i][j] + bv;
          if (DOCELU) v = v > 0.f ? v : 0.1f * (__expf(10.f * v) - 1.f);
          sOut[(m * 16 + q * 4 + j) * NOUT + col] = f2bf(v);
        }
      }
    }
  }
}

#define LDSA 49152  // 64*384*2 : aev tile, reused as h2 [64][128]
#define LDSH 20480  // 64*160*2 : h1, reused as h3 [64][96]

__global__ __launch_bounds__(256) void k_mlp(
    const int* __restrict__ hdr, const int* __restrict__ sorted,
    const float* __restrict__ aev,
    const unsigned short* __restrict__ Wt1, const unsigned short* __restrict__ Wt2,
    const unsigned short* __restrict__ Wt3,
    const float* __restrict__ b1, const float* __restrict__ b2,
    const float* __restrict__ b3,
    const float* __restrict__ W4, const float* __restrict__ b4,
    float* __restrict__ energy) {
  __shared__ __align__(16) unsigned char smem[LDSA + LDSH];
  unsigned short* sA = (unsigned short*)smem;
  unsigned short* sH = (unsigned short*)(smem + LDSA);

  const int tid = threadIdx.x, wave = tid >> 6, lane = tid & 63;
  const int t64 = blockIdx.x << 6;
  if (t64 >= hdr[13]) return;
  const int s = (t64 >= hdr[10]) + (t64 >= hdr[11]) + (t64 >= hdr[12]);
  const int seg0 = t64 - hdr[9 + s];
  const int base = hdr[4 + s] + seg0;
  const int cnt = hdr[s];

  // stage gathered aev rows (fp32 -> bf16), wave w stages rows 16w..16w+15
  for (int rr = 0; rr < 16; ++rr) {
    const int row = (wave << 4) + rr;
    const bool valid = (seg0 + row) < cnt;
    const int atom = valid ? sorted[base + row] : 0;
    const float4* src = (const float4*)(aev + (size_t)atom * DIM);
#pragma unroll
    for (int jj = 0; jj < 2; ++jj) {
      const int idx = lane + (jj << 6);
      if (idx < 96) {
        float4 v = valid ? src[idx] : make_float4(0.f, 0.f, 0.f, 0.f);
        uint2 w;
        w.x = (unsigned)f2bf(v.x) | ((unsigned)f2bf(v.y) << 16);
        w.y = (unsigned)f2bf(v.z) | ((unsigned)f2bf(v.w) << 16);
        *(uint2*)(sA + row * DIM + idx * 4) = w;
      }
    }
  }
  __syncthreads();

  layer<DIM, NH1, true>(sA, Wt1 + s * NH1 * DIM, b1 + s * NH1, sH, wave, lane);
  __syncthreads();
  layer<NH1, NH2, true>(sH, Wt2 + s * NH2 * NH1, b2 + s * NH2, sA, wave, lane);
  __syncthreads();
  layer<NH2, NH3, true>(sA, Wt3 + s * NH3 * NH2, b3 + s * NH3, sH, wave, lane);
  __syncthreads();

  // layer 4: y = h3 . W4 + b4, fp32; per-conformation atomic sum
  if (tid < 64) {
    const int row = tid;
    if (seg0 + row < cnt) {
      const float* w4 = W4 + s * NH3;
      float acc = b4[s];
      for (int k = 0; k < NH3; ++k) acc += bf2f(sH[row * NH3 + k]) * w4[k];
      const int atom = sorted[base + row];
      atomicAdd(&energy[atom >> 6], acc);
    }
  }
}

// ---------------- launch ----------------

extern "C" void kernel_launch(void* const* d_in, const int* in_sizes, int n_in,
                              void* d_out, int out_size, void* d_ws, size_t ws_size,
                              hipStream_t stream) {
  const int* species = (const int*)d_in[0];
  const float* aev = (const float*)d_in[1];
  const float* W1 = (const float*)d_in[2];
  const float* b1 = (const float*)d_in[3];
  const float* W2 = (const float*)d_in[4];
  const float* b2 = (const float*)d_in[5];
  const float* W3 = (const float*)d_in[6];
  const float* b3 = (const float*)d_in[7];
  const float* W4 = (const float*)d_in[8];
  const float* b4 = (const float*)d_in[9];

  int* hdr = (int*)d_ws;
  int* sorted = (int*)((char*)d_ws + 128);
  unsigned short* Wt1 = (unsigned short*)((char*)d_ws + 128 + (size_t)NATOM * 4);
  unsigned short* Wt2 = Wt1 + NSP * NH1 * DIM;
  unsigned short* Wt3 = Wt2 + NSP * NH2 * NH1;

  float* out_species = (float*)d_out;
  float* energy = (float*)d_out + NATOM;

  hipMemsetAsync(d_ws, 0, 128, stream);
  hipMemsetAsync(energy, 0, NCONF * sizeof(float), stream);

  k_count<<<NATOM / 256, 256, 0, stream>>>(species, hdr);
  k_scan<<<1, 64, 0, stream>>>(hdr);
  k_scatter<<<NATOM / 256, 256, 0, stream>>>(species, hdr, sorted);
  k_wcvt<<<(NSP * NH1 * DIM + 255) / 256, 256, 0, stream>>>(W1, Wt1, DIM, NH1, NSP * NH1 * DIM);
  k_wcvt<<<(NSP * NH2 * NH1 + 255) / 256, 256, 0, stream>>>(W2, Wt2, NH1, NH2, NSP * NH2 * NH1);
  k_wcvt<<<(NSP * NH3 * NH2 + 255) / 256, 256, 0, stream>>>(W3, Wt3, NH2, NH3, NSP * NH3 * NH2);
  k_species<<<NATOM / 256, 256, 0, stream>>>(species, out_species);

  k_mlp<<<2052, 256, 0, stream>>>(hdr, sorted, aev, Wt1, Wt2, Wt3,
                                  b1, b2, b3, W4, b4, energy);
}

// Round 4
// 503.973 us; speedup vs baseline: 3.4503x; 3.4503x over previous
//
#include <hip/hip_runtime.h>
#include <hip/hip_bf16.h>

// ANI species-expert MLP, fused. Pipeline per launch:
//   memset hdr + energies
//   k_count (fused species->float out) / k_scan / k_scatter :
//       counting-sort atom indices by species, ballot+LDS aggregation
//       (R1: 131072 global atomics on 4 words = 705us each; now 4/block)
//   k_wcvt x3 : W1..W3 fp32 [S][K][N] -> bf16 transposed [S][N][K]
//   k_mlp     : per 64-atom same-species tile, 4-layer MFMA MLP.
//               LDS tiles PADDED (392/168/136/104) to break the 8/16-way
//               bank conflicts of the natural strides (384/160/128/96).
//               atomicAdd per-conformation energy into d_out[N:N+2048]

#define NSP   4
#define DIM   384
#define NH1   160
#define NH2   128
#define NH3   96
// padded LDS row strides: bank step 2-way (free, m136) and 16B-aligned
#define DIMP  392
#define NH1P  168
#define NH2P  136
#define NH3P  104
#define NATOM (2048 * 64)
#define NCONF 2048

typedef __attribute__((ext_vector_type(8))) short short8;
typedef __attribute__((ext_vector_type(4))) float f32x4;

__device__ __forceinline__ unsigned short f2bf(float f) {
  union { float f; unsigned u; } v; v.f = f;
  unsigned r = v.u + 0x7fffu + ((v.u >> 16) & 1u);   // RNE
  return (unsigned short)(r >> 16);
}
__device__ __forceinline__ float bf2f(unsigned short h) {
  union { unsigned u; float f; } v; v.u = ((unsigned)h) << 16;
  return v.f;
}

// ---------------- sort / convert helpers ----------------

// counts per species via wave ballot -> LDS -> 4 global atomics per block.
// Also emits species as float (output 0) in the same pass.
__global__ void k_count(const int* __restrict__ sp, int* __restrict__ hdr,
                        float* __restrict__ out_species) {
  const int i = blockIdx.x * 256 + threadIdx.x;
  const int s = sp[i];
  out_species[i] = (float)s;
  __shared__ int cnt[NSP];
  if (threadIdx.x < NSP) cnt[threadIdx.x] = 0;
  __syncthreads();
  const int lane = threadIdx.x & 63;
#pragma unroll
  for (int sv = 0; sv < NSP; ++sv) {
    unsigned long long m = __ballot(s == sv);
    if (lane == 0) atomicAdd(&cnt[sv], __popcll(m));
  }
  __syncthreads();
  if (threadIdx.x < NSP) atomicAdd(&hdr[threadIdx.x], cnt[threadIdx.x]);
}

// hdr layout (ints): [0..3] counts, [4..8] real offsets, [9..13] padded offsets,
//                    [14..17] scatter cursors
__global__ void k_scan(int* hdr) {
  if (threadIdx.x == 0 && blockIdx.x == 0) {
    int ro = 0, po = 0;
    for (int s = 0; s < NSP; ++s) {
      hdr[4 + s]  = ro;
      hdr[9 + s]  = po;
      hdr[14 + s] = ro;
      int cs = hdr[s];
      ro += cs;
      po += (cs + 63) & ~63;
    }
    hdr[8]  = ro;
    hdr[13] = po;
  }
}

// rank within (wave, species) via ballot; per-wave counts in LDS; one cursor
// atomic per species per block. Order within species is arbitrary (gather only).
__global__ void k_scatter(const int* __restrict__ sp, int* __restrict__ hdr,
                          int* __restrict__ sorted) {
  const int i = blockIdx.x * 256 + threadIdx.x;
  const int s = sp[i];
  const int lane = threadIdx.x & 63, wave = threadIdx.x >> 6;
  __shared__ int wcnt[4][NSP];
  __shared__ int wbase[4][NSP];
  const unsigned long long below = (1ull << lane) - 1ull;
  int myrank = 0;
#pragma unroll
  for (int sv = 0; sv < NSP; ++sv) {
    unsigned long long m = __ballot(s == sv);
    if (sv == s) myrank = __popcll(m & below);
    if (lane == 0) wcnt[wave][sv] = __popcll(m);
  }
  __syncthreads();
  if (threadIdx.x < NSP) {
    const int sv = threadIdx.x;
    const int tot = wcnt[0][sv] + wcnt[1][sv] + wcnt[2][sv] + wcnt[3][sv];
    int off = atomicAdd(&hdr[14 + sv], tot);
#pragma unroll
    for (int w = 0; w < 4; ++w) { wbase[w][sv] = off; off += wcnt[w][sv]; }
  }
  __syncthreads();
  sorted[wbase[wave][s] + myrank] = i;
}

// dst[s][n][k] = bf16(src[s][k][n])
__global__ void k_wcvt(const float* __restrict__ src, unsigned short* __restrict__ dst,
                       int K, int N, int total) {
  int i = blockIdx.x * 256 + threadIdx.x;
  if (i < total) {
    int kn = K * N;
    int s = i / kn, r = i - s * kn;
    int n = r / K, k = r - n * K;
    dst[i] = f2bf(src[s * kn + k * N + n]);
  }
}

// ---------------- fused MLP ----------------

// One 16x16 col-frag set per wave (f = wave, wave+4, ...), all 4 row-frags.
// A (LDS, bf16 [64][KP] padded) -> 4x ds_read_b128 per k-step, 2-way banks.
// B from GLOBAL pre-transposed bf16 [NOUT][K] (packed): one dwordx4 per frag
// (L2-cached, 16 full cache lines per wave instruction). No k-loop syncs.
template <int K, int KP, int NOUT, int NOUTP, bool DOCELU>
__device__ __forceinline__ void layer(const unsigned short* __restrict__ sIn,
                                      const unsigned short* __restrict__ Wt,
                                      const float* __restrict__ bias,
                                      unsigned short* __restrict__ sOut,
                                      int wave, int lane) {
  constexpr int NF = NOUT / 16;
  constexpr int NOWN = (NF + 3) / 4;
  const int c = lane & 15, q = lane >> 4;
  const int kb = q * 8;

  f32x4 acc[4][NOWN];
#pragma unroll
  for (int m = 0; m < 4; ++m)
#pragma unroll
    for (int i = 0; i < NOWN; ++i) acc[m][i] = (f32x4){0.f, 0.f, 0.f, 0.f};

  for (int k0 = 0; k0 < K; k0 += 32) {
    short8 a[4];
#pragma unroll
    for (int m = 0; m < 4; ++m)
      a[m] = *(const short8*)(sIn + (m * 16 + c) * KP + k0 + kb);
#pragma unroll
    for (int i = 0; i < NOWN; ++i) {
      int f = wave + 4 * i;
      if (f < NF) {
        short8 b = *(const short8*)(Wt + (f * 16 + c) * K + k0 + kb);
#pragma unroll
        for (int m = 0; m < 4; ++m)
          acc[m][i] = __builtin_amdgcn_mfma_f32_16x16x32_bf16(a[m], b, acc[m][i], 0, 0, 0);
      }
    }
  }

  // epilogue: bias + CELU(alpha=0.1), bf16 -> LDS
  // D layout: col = lane&15 (+16f), row = 4*(lane>>4)+j (+16m)   [m89-verified]
#pragma unroll
  for (int i = 0; i < NOWN; ++i) {
    int f = wave + 4 * i;
    if (f < NF) {
      int col = f * 16 + c;
      float bv = bias[col];
#pragma unroll
      for (int m = 0; m < 4; ++m) {
#pragma unroll
        for (int j = 0; j < 4; ++j) {
          float v = acc[m][i][j] + bv;
          if (DOCELU) v = v > 0.f ? v : 0.1f * (__expf(10.f * v) - 1.f);
          sOut[(m * 16 + q * 4 + j) * NOUTP + col] = f2bf(v);
        }
      }
    }
  }
}

#define LDSA (64 * DIMP * 2)  // 50176: aev tile, reused as h2 [64][NH2P]
#define LDSH (64 * NH1P * 2)  // 21504: h1, reused as h3 [64][NH3P]

__global__ __launch_bounds__(256) void k_mlp(
    const int* __restrict__ hdr, const int* __restrict__ sorted,
    const float* __restrict__ aev,
    const unsigned short* __restrict__ Wt1, const unsigned short* __restrict__ Wt2,
    const unsigned short* __restrict__ Wt3,
    const float* __restrict__ b1, const float* __restrict__ b2,
    const float* __restrict__ b3,
    const float* __restrict__ W4, const float* __restrict__ b4,
    float* __restrict__ energy) {
  __shared__ __align__(16) unsigned char smem[LDSA + LDSH];
  unsigned short* sA = (unsigned short*)smem;
  unsigned short* sH = (unsigned short*)(smem + LDSA);

  const int tid = threadIdx.x, wave = tid >> 6, lane = tid & 63;
  const int t64 = blockIdx.x << 6;
  if (t64 >= hdr[13]) return;
  const int s = (t64 >= hdr[10]) + (t64 >= hdr[11]) + (t64 >= hdr[12]);
  const int seg0 = t64 - hdr[9 + s];
  const int base = hdr[4 + s] + seg0;
  const int cnt = hdr[s];

  // stage gathered aev rows (fp32 -> bf16), wave w stages rows 16w..16w+15
  for (int rr = 0; rr < 16; ++rr) {
    const int row = (wave << 4) + rr;
    const bool valid = (seg0 + row) < cnt;
    const int atom = valid ? sorted[base + row] : 0;
    const float4* src = (const float4*)(aev + (size_t)atom * DIM);
#pragma unroll
    for (int jj = 0; jj < 2; ++jj) {
      const int idx = lane + (jj << 6);
      if (idx < 96) {
        float4 v = valid ? src[idx] : make_float4(0.f, 0.f, 0.f, 0.f);
        uint2 w;
        w.x = (unsigned)f2bf(v.x) | ((unsigned)f2bf(v.y) << 16);
        w.y = (unsigned)f2bf(v.z) | ((unsigned)f2bf(v.w) << 16);
        *(uint2*)(sA + row * DIMP + idx * 4) = w;
      }
    }
  }
  __syncthreads();

  layer<DIM, DIMP, NH1, NH1P, true>(sA, Wt1 + s * NH1 * DIM, b1 + s * NH1, sH, wave, lane);
  __syncthreads();
  layer<NH1, NH1P, NH2, NH2P, true>(sH, Wt2 + s * NH2 * NH1, b2 + s * NH2, sA, wave, lane);
  __syncthreads();
  layer<NH2, NH2P, NH3, NH3P, true>(sA, Wt3 + s * NH3 * NH2, b3 + s * NH3, sH, wave, lane);
  __syncthreads();

  // layer 4: y = h3 . W4 + b4; 4 threads per row, vector LDS reads, shfl reduce
  {
    const int row = tid >> 2, part = tid & 3;
    if (seg0 + row < cnt) {
      const float* w4 = W4 + s * NH3 + part * 24;
      const unsigned short* hrow = sH + row * NH3P + part * 24;
      float acc = 0.f;
#pragma unroll
      for (int u = 0; u < 3; ++u) {
        short8 h = *(const short8*)(hrow + u * 8);
#pragma unroll
        for (int e = 0; e < 8; ++e)
          acc += bf2f((unsigned short)h[e]) * w4[u * 8 + e];
      }
      acc += __shfl_xor(acc, 1);
      acc += __shfl_xor(acc, 2);
      if (part == 0) {
        const int atom = sorted[base + row];
        atomicAdd(&energy[atom >> 6], acc + b4[s]);
      }
    }
  }
}

// ---------------- launch ----------------

extern "C" void kernel_launch(void* const* d_in, const int* in_sizes, int n_in,
                              void* d_out, int out_size, void* d_ws, size_t ws_size,
                              hipStream_t stream) {
  const int* species = (const int*)d_in[0];
  const float* aev = (const float*)d_in[1];
  const float* W1 = (const float*)d_in[2];
  const float* b1 = (const float*)d_in[3];
  const float* W2 = (const float*)d_in[4];
  const float* b2 = (const float*)d_in[5];
  const float* W3 = (const float*)d_in[6];
  const float* b3 = (const float*)d_in[7];
  const float* W4 = (const float*)d_in[8];
  const float* b4 = (const float*)d_in[9];

  int* hdr = (int*)d_ws;
  int* sorted = (int*)((char*)d_ws + 128);
  unsigned short* Wt1 = (unsigned short*)((char*)d_ws + 128 + (size_t)NATOM * 4);
  unsigned short* Wt2 = Wt1 + NSP * NH1 * DIM;
  unsigned short* Wt3 = Wt2 + NSP * NH2 * NH1;

  float* out_species = (float*)d_out;
  float* energy = (float*)d_out + NATOM;

  hipMemsetAsync(d_ws, 0, 128, stream);
  hipMemsetAsync(energy, 0, NCONF * sizeof(float), stream);

  k_count<<<NATOM / 256, 256, 0, stream>>>(species, hdr, out_species);
  k_scan<<<1, 64, 0, stream>>>(hdr);
  k_scatter<<<NATOM / 256, 256, 0, stream>>>(species, hdr, sorted);
  k_wcvt<<<(NSP * NH1 * DIM + 255) / 256, 256, 0, stream>>>(W1, Wt1, DIM, NH1, NSP * NH1 * DIM);
  k_wcvt<<<(NSP * NH2 * NH1 + 255) / 256, 256, 0, stream>>>(W2, Wt2, NH1, NH2, NSP * NH2 * NH1);
  k_wcvt<<<(NSP * NH3 * NH2 + 255) / 256, 256, 0, stream>>>(W3, Wt3, NH2, NH3, NSP * NH3 * NH2);

  k_mlp<<<2052, 256, 0, stream>>>(hdr, sorted, aev, Wt1, Wt2, Wt3,
                                  b1, b2, b3, W4, b4, energy);
}

// Round 11
// 461.930 us; speedup vs baseline: 3.7643x; 1.0910x over previous
//
#include <hip/hip_runtime.h>
#include <hip/hip_bf16.h>

// ANI species-expert MLP, fused. Pipeline per launch:
//   memset hdr + energies
//   k_count (fused species->float out) / k_scan / k_scatter :
//       counting-sort atom indices by species, ballot+LDS aggregation
//   k_wcvt_all : W1..W3 fp32 [S][K][N] -> bf16 transposed [S][N][K], one launch
//   k_mlp      : WAVE-PRIVATE design (R5): each wave owns 16 atoms end-to-end.
//                Layer1 A-frags straight from global fp32 (cvt_pk to bf16),
//                h1/h2/h3 transposed through wave-private LDS (9.7KB/wave),
//                ZERO __syncthreads. 38.9KB LDS/block -> 4 blocks/CU.
//                (R4: 71.7KB LDS, 2 blocks/CU, 5 barriers -> latency-bound,
//                 MfmaUtil 3.7%, Occ 20%, 263us.)

#define NSP   4
#define DIM   384
#define NH1   160
#define NH2   128
#define NH3   96
// padded LDS row strides (elements): conflict-free ds_read_b128
#define NH1P  168
#define NH2P  136
#define NH3P  104
#define NATOM (2048 * 64)
#define NCONF 2048

// per-wave LDS: bufX (h1, later h3) + bufY (h2)
#define XBYTES (16 * NH1P * 2)          // 5376
#define YBYTES (16 * NH2P * 2)          // 4352
#define WAVE_LDS (XBYTES + YBYTES)      // 9728
#define BLOCK_LDS (4 * WAVE_LDS)        // 38912

typedef __attribute__((ext_vector_type(8))) short short8;
typedef __attribute__((ext_vector_type(4))) float f32x4;

__device__ __forceinline__ unsigned short f2bf(float f) {
  union { float f; unsigned u; } v; v.f = f;
  unsigned r = v.u + 0x7fffu + ((v.u >> 16) & 1u);   // RNE
  return (unsigned short)(r >> 16);
}
__device__ __forceinline__ float bf2f(unsigned short h) {
  union { unsigned u; float f; } v; v.u = ((unsigned)h) << 16;
  return v.f;
}
// 8 fp32 -> 8 bf16 (RNE, v_cvt_pk_bf16_f32 via compiler)
__device__ __forceinline__ short8 cvt8(float4 x, float4 y) {
  union { short8 v; __hip_bfloat162 h[4]; } u;
  u.h[0] = __float22bfloat162_rn(make_float2(x.x, x.y));
  u.h[1] = __float22bfloat162_rn(make_float2(x.z, x.w));
  u.h[2] = __float22bfloat162_rn(make_float2(y.x, y.y));
  u.h[3] = __float22bfloat162_rn(make_float2(y.z, y.w));
  return u.v;
}
__device__ __forceinline__ float celu01(float v) {
  return v > 0.f ? v : 0.1f * (__expf(10.f * v) - 1.f);
}

// ---------------- sort / convert helpers ----------------

__global__ void k_count(const int* __restrict__ sp, int* __restrict__ hdr,
                        float* __restrict__ out_species) {
  const int i = blockIdx.x * 256 + threadIdx.x;
  const int s = sp[i];
  out_species[i] = (float)s;
  __shared__ int cnt[NSP];
  if (threadIdx.x < NSP) cnt[threadIdx.x] = 0;
  __syncthreads();
  const int lane = threadIdx.x & 63;
#pragma unroll
  for (int sv = 0; sv < NSP; ++sv) {
    unsigned long long m = __ballot(s == sv);
    if (lane == 0) atomicAdd(&cnt[sv], __popcll(m));
  }
  __syncthreads();
  if (threadIdx.x < NSP) atomicAdd(&hdr[threadIdx.x], cnt[threadIdx.x]);
}

// hdr layout (ints): [0..3] counts, [4..8] real offsets, [9..13] padded offsets,
//                    [14..17] scatter cursors
__global__ void k_scan(int* hdr) {
  if (threadIdx.x == 0 && blockIdx.x == 0) {
    int ro = 0, po = 0;
    for (int s = 0; s < NSP; ++s) {
      hdr[4 + s]  = ro;
      hdr[9 + s]  = po;
      hdr[14 + s] = ro;
      int cs = hdr[s];
      ro += cs;
      po += (cs + 63) & ~63;
    }
    hdr[8]  = ro;
    hdr[13] = po;
  }
}

__global__ void k_scatter(const int* __restrict__ sp, int* __restrict__ hdr,
                          int* __restrict__ sorted) {
  const int i = blockIdx.x * 256 + threadIdx.x;
  const int s = sp[i];
  const int lane = threadIdx.x & 63, wave = threadIdx.x >> 6;
  __shared__ int wcnt[4][NSP];
  __shared__ int wbase[4][NSP];
  const unsigned long long below = (1ull << lane) - 1ull;
  int myrank = 0;
#pragma unroll
  for (int sv = 0; sv < NSP; ++sv) {
    unsigned long long m = __ballot(s == sv);
    if (sv == s) myrank = __popcll(m & below);
    if (lane == 0) wcnt[wave][sv] = __popcll(m);
  }
  __syncthreads();
  if (threadIdx.x < NSP) {
    const int sv = threadIdx.x;
    const int tot = wcnt[0][sv] + wcnt[1][sv] + wcnt[2][sv] + wcnt[3][sv];
    int off = atomicAdd(&hdr[14 + sv], tot);
#pragma unroll
    for (int w = 0; w < 4; ++w) { wbase[w][sv] = off; off += wcnt[w][sv]; }
  }
  __syncthreads();
  sorted[wbase[wave][s] + myrank] = i;
}

// all three weight transposes in one launch. dst[s][n][k] = bf16(src[s][k][n])
#define N1TOT (NSP * NH1 * DIM)   // 245760
#define N2TOT (NSP * NH2 * NH1)   // 81920
#define N3TOT (NSP * NH3 * NH2)   // 49152
#define NWTOT (N1TOT + N2TOT + N3TOT)

__device__ __forceinline__ void wcvt1(const float* src, unsigned short* dst,
                                      int i, int K, int N) {
  int kn = K * N;
  int s = i / kn, r = i - s * kn;
  int n = r / K, k = r - n * K;
  dst[i] = f2bf(src[s * kn + k * N + n]);
}

__global__ void k_wcvt_all(const float* __restrict__ W1, const float* __restrict__ W2,
                           const float* __restrict__ W3,
                           unsigned short* __restrict__ Wt1, unsigned short* __restrict__ Wt2,
                           unsigned short* __restrict__ Wt3) {
  int i = blockIdx.x * 256 + threadIdx.x;
  if (i < N1TOT) wcvt1(W1, Wt1, i, DIM, NH1);
  else if (i < N1TOT + N2TOT) wcvt1(W2, Wt2, i - N1TOT, NH1, NH2);
  else if (i < NWTOT) wcvt1(W3, Wt3, i - N1TOT - N2TOT, NH2, NH3);
}

// ---------------- fused MLP (wave-private) ----------------

// Layers 2/3: A from wave-private LDS (row-major, padded stride), B from global
// pre-transposed bf16 [NOUT][K]. All NF col-frags per wave. No syncs.
template <int K, int KP, int NOUT, int NOUTP>
__device__ __forceinline__ void layerL(const unsigned short* __restrict__ sIn,
                                       const unsigned short* __restrict__ Wt,
                                       const float* __restrict__ bias,
                                       unsigned short* __restrict__ sOut,
                                       int c, int q) {
  constexpr int NF = NOUT / 16;
  f32x4 acc[NF];
#pragma unroll
  for (int f = 0; f < NF; ++f) acc[f] = (f32x4){0.f, 0.f, 0.f, 0.f};

#pragma unroll 2
  for (int k0 = 0; k0 < K; k0 += 32) {
    short8 a = *(const short8*)(sIn + c * KP + k0 + q * 8);
#pragma unroll
    for (int f = 0; f < NF; ++f) {
      short8 b = *(const short8*)(Wt + (f * 16 + c) * K + k0 + q * 8);
      acc[f] = __builtin_amdgcn_mfma_f32_16x16x32_bf16(a, b, acc[f], 0, 0, 0);
    }
  }
  // D layout: col = lane&15, row = 4*(lane>>4)+j   [m89-verified]
#pragma unroll
  for (int f = 0; f < NF; ++f) {
    float bv = bias[f * 16 + c];
#pragma unroll
    for (int j = 0; j < 4; ++j)
      sOut[(4 * q + j) * NOUTP + f * 16 + c] = f2bf(celu01(acc[f][j] + bv));
  }
}

__global__ __launch_bounds__(256, 4) void k_mlp(
    const int* __restrict__ hdr, const int* __restrict__ sorted,
    const float* __restrict__ aev,
    const unsigned short* __restrict__ Wt1, const unsigned short* __restrict__ Wt2,
    const unsigned short* __restrict__ Wt3,
    const float* __restrict__ b1, const float* __restrict__ b2,
    const float* __restrict__ b3,
    const float* __restrict__ W4, const float* __restrict__ b4,
    float* __restrict__ energy) {
  __shared__ __align__(16) unsigned char smem[BLOCK_LDS];
  const int tid = threadIdx.x, wave = tid >> 6, lane = tid & 63;
  const int c = lane & 15, q = lane >> 4;
  unsigned short* hX = (unsigned short*)(smem + wave * WAVE_LDS);            // h1, h3
  unsigned short* hY = (unsigned short*)(smem + wave * WAVE_LDS + XBYTES);   // h2

  const int t64 = blockIdx.x << 6;
  if (t64 >= hdr[13]) return;
  const int s = (t64 >= hdr[10]) + (t64 >= hdr[11]) + (t64 >= hdr[12]);
  const int seg0 = t64 - hdr[9 + s] + wave * 16;  // this wave's first row in segment
  const int cnt  = hdr[s];
  const bool valid = (seg0 + c) < cnt;
  const int sidx = valid ? (hdr[4 + s] + seg0 + c) : hdr[4 + s];
  const int atom = sorted[sidx];                  // lane c's atom (q-duplicated)
  const float* __restrict__ arow = aev + (size_t)atom * DIM;

  // ---- layer 1: A direct from global fp32, K=384, NF=10 ----
  {
    const unsigned short* __restrict__ Wt = Wt1 + s * NH1 * DIM;
    f32x4 acc[10];
#pragma unroll
    for (int f = 0; f < 10; ++f) acc[f] = (f32x4){0.f, 0.f, 0.f, 0.f};
#pragma unroll 2
    for (int k0 = 0; k0 < DIM; k0 += 32) {
      float4 fa = *(const float4*)(arow + k0 + q * 8);
      float4 fb = *(const float4*)(arow + k0 + q * 8 + 4);
      short8 a = cvt8(fa, fb);
#pragma unroll
      for (int f = 0; f < 10; ++f) {
        short8 b = *(const short8*)(Wt + (f * 16 + c) * DIM + k0 + q * 8);
        acc[f] = __builtin_amdgcn_mfma_f32_16x16x32_bf16(a, b, acc[f], 0, 0, 0);
      }
    }
    const float* bias = b1 + s * NH1;
#pragma unroll
    for (int f = 0; f < 10; ++f) {
      float bv = bias[f * 16 + c];
#pragma unroll
      for (int j = 0; j < 4; ++j)
        hX[(4 * q + j) * NH1P + f * 16 + c] = f2bf(celu01(acc[f][j] + bv));
    }
  }

  // ---- layer 2: h1 -> h2 ----
  layerL<NH1, NH1P, NH2, NH2P>(hX, Wt2 + s * NH2 * NH1, b2 + s * NH2, hY, c, q);
  // ---- layer 3: h2 -> h3 (back into X) ----
  layerL<NH2, NH2P, NH3, NH3P>(hY, Wt3 + s * NH3 * NH2, b3 + s * NH3, hX, c, q);

  // ---- layer 4: y = h3 . W4 + b4 ; lane (c,q): row c, 24-elem slice q ----
  {
    const float* __restrict__ w4 = W4 + s * NH3 + q * 24;
    const unsigned short* __restrict__ hrow = hX + c * NH3P + q * 24;
    float dot = 0.f;
#pragma unroll
    for (int u = 0; u < 3; ++u) {
      short8 h = *(const short8*)(hrow + u * 8);
#pragma unroll
      for (int e = 0; e < 8; ++e)
        dot += bf2f((unsigned short)h[e]) * w4[u * 8 + e];
    }
    dot += __shfl_xor(dot, 16);
    dot += __shfl_xor(dot, 32);
    if (q == 0 && valid)
      atomicAdd(&energy[atom >> 6], dot + b4[s]);
  }
}

// ---------------- launch ----------------

extern "C" void kernel_launch(void* const* d_in, const int* in_sizes, int n_in,
                              void* d_out, int out_size, void* d_ws, size_t ws_size,
                              hipStream_t stream) {
  const int* species = (const int*)d_in[0];
  const float* aev = (const float*)d_in[1];
  const float* W1 = (const float*)d_in[2];
  const float* b1 = (const float*)d_in[3];
  const float* W2 = (const float*)d_in[4];
  const float* b2 = (const float*)d_in[5];
  const float* W3 = (const float*)d_in[6];
  const float* b3 = (const float*)d_in[7];
  const float* W4 = (const float*)d_in[8];
  const float* b4 = (const float*)d_in[9];

  int* hdr = (int*)d_ws;
  int* sorted = (int*)((char*)d_ws + 128);
  unsigned short* Wt1 = (unsigned short*)((char*)d_ws + 128 + (size_t)NATOM * 4);
  unsigned short* Wt2 = Wt1 + N1TOT;
  unsigned short* Wt3 = Wt2 + N2TOT;

  float* out_species = (float*)d_out;
  float* energy = (float*)d_out + NATOM;

  hipMemsetAsync(d_ws, 0, 128, stream);
  hipMemsetAsync(energy, 0, NCONF * sizeof(float), stream);

  k_count<<<NATOM / 256, 256, 0, stream>>>(species, hdr, out_species);
  k_scan<<<1, 64, 0, stream>>>(hdr);
  k_scatter<<<NATOM / 256, 256, 0, stream>>>(species, hdr, sorted);
  k_wcvt_all<<<(NWTOT + 255) / 256, 256, 0, stream>>>(W1, W2, W3, Wt1, Wt2, Wt3);

  k_mlp<<<2052, 256, 0, stream>>>(hdr, sorted, aev, Wt1, Wt2, Wt3,
                                  b1, b2, b3, W4, b4, energy);
}